// Round 4
// baseline (188.432 us; speedup 1.0000x reference)
//
#include <hip/hip_runtime.h>

#define N_ROWS 8192
#define NX     4096
#define DIM    512
#define BT     128          // block tile (rows & cols)
#define NT     64           // N_ROWS / BT tiles per side
#define NB     (NT * (NT + 1) / 2)   // 2080 upper-triangle tiles
#define BK     32           // K elements per stage (64 B per row)
#define NCOLB  128          // colsum partial blocks (64 rows each)

typedef __bf16 bf16_t;
typedef bf16_t bf16x8 __attribute__((ext_vector_type(8)));
typedef bf16_t bf16x4 __attribute__((ext_vector_type(4)));
typedef float  f32x4  __attribute__((ext_vector_type(4)));

#if __has_builtin(__builtin_amdgcn_exp2f)
  #define EXP2F __builtin_amdgcn_exp2f
#else
  #define EXP2F exp2f
#endif

// ws layout (bytes):
//   0       sqrow[8192]          float   (32768)
//   32768   cvals[5]             float   (20, pad to 32)
//   32800   acc                  double  (8)
//   32808   done                 uint    (4, pad)
//   32832   colpart[128][512]    float   (262144)
//   294976  Zh[8192*512]         bf16    (8388608)

__device__ __forceinline__ const float* zrow(const float* X, const float* Y, int r) {
    return (r < NX) ? (X + (size_t)r * DIM) : (Y + (size_t)(r - NX) * DIM);
}

__device__ __forceinline__ void gload_lds16(const bf16_t* g, bf16_t* l) {
    __builtin_amdgcn_global_load_lds(
        (__attribute__((address_space(1))) void*)(void*)(g),
        (__attribute__((address_space(3))) void*)(void*)(l), 16, 0, 0);
}

// blocks [0,2048): convert 4 rows to bf16 + exact fp32 row norms
// blocks [2048,2176): colsum partial over 64-row slab -> colpart[b][512]
__global__ void k_prepall(const float* __restrict__ X, const float* __restrict__ Y,
                          bf16_t* __restrict__ Zh, float* __restrict__ sqrow,
                          float* __restrict__ colpart) {
    int t = threadIdx.x;
    if (blockIdx.x < 2048) {
        int wv = t >> 6, lane = t & 63;
        int row = blockIdx.x * 4 + wv;
        const float4* z4 = (const float4*)zrow(X, Y, row);
        float4 a = z4[lane], b = z4[lane + 64];
        bf16x4 ha = {(bf16_t)a.x, (bf16_t)a.y, (bf16_t)a.z, (bf16_t)a.w};
        bf16x4 hb = {(bf16_t)b.x, (bf16_t)b.y, (bf16_t)b.z, (bf16_t)b.w};
        *(bf16x4*)(Zh + (size_t)row * DIM + lane * 4) = ha;
        *(bf16x4*)(Zh + (size_t)row * DIM + 256 + lane * 4) = hb;
        float s = a.x*a.x + a.y*a.y + a.z*a.z + a.w*a.w
                + b.x*b.x + b.y*b.y + b.z*b.z + b.w*b.w;
        #pragma unroll
        for (int off = 32; off > 0; off >>= 1) s += __shfl_down(s, off);
        if (lane == 0) sqrow[row] = s;
    } else {
        int b2 = blockIdx.x - 2048;
        int c = t * 2;
        int r0 = b2 * 64;
        float s0 = 0.f, s1 = 0.f;
        #pragma unroll 4
        for (int r = r0; r < r0 + 64; ++r) {
            float2 v = *(const float2*)(zrow(X, Y, r) + c);
            s0 += v.x; s1 += v.y;
        }
        colpart[b2 * 512 + c]     = s0;
        colpart[b2 * 512 + c + 1] = s1;
    }
}

// S1 = sum sqrow; CS = sum_d (sum_b colpart[b][d])^2; bw, cvals; zero acc/done
__global__ void k_bw(const float* __restrict__ sqrow, const float* __restrict__ colpart,
                     float* cvals, double* acc, unsigned* done) {
    __shared__ double red[256];
    int t = threadIdx.x;
    double s1 = 0.0;
    for (int i = t; i < N_ROWS; i += 256) s1 += (double)sqrow[i];
    double cs = 0.0;
    for (int d = t; d < DIM; d += 256) {
        float tot = 0.f;
        #pragma unroll 4
        for (int b = 0; b < NCOLB; ++b) tot += colpart[b * 512 + d];
        cs += (double)tot * (double)tot;
    }
    red[t] = s1; __syncthreads();
    for (int off = 128; off > 0; off >>= 1) { if (t < off) red[t] += red[t + off]; __syncthreads(); }
    double S1 = red[0]; __syncthreads();
    red[t] = cs; __syncthreads();
    for (int off = 128; off > 0; off >>= 1) { if (t < off) red[t] += red[t + off]; __syncthreads(); }
    if (t == 0) {
        double CS = red[0];
        double n = (double)N_ROWS;
        double sumD2 = 2.0 * n * S1 - 2.0 * CS;
        double bw = sumD2 / (n * n - n);
        const double LOG2E = 1.4426950408889634;
        double mult = 0.25;
        for (int k = 0; k < 5; ++k) {
            cvals[k] = (float)(-LOG2E / (bw * mult));
            mult *= 2.0;
        }
        *acc = 0.0;
        *done = 0u;
    }
}

// 1D triangular grid, 128x128 tile, double-buffered LDS (one barrier/iter),
// global_load_lds width=16 with global-side XOR swizzle (conflict-free frags),
// fused finalize via ticket counter.
__global__ __launch_bounds__(256) void k_pair(const bf16_t* __restrict__ Zh,
                                              const float* __restrict__ sqrow,
                                              const float* __restrict__ cvals,
                                              double* acc, unsigned* done,
                                              float* out) {
    // triangular decode: row ti has NT-ti tiles; S(ti) = ti*NT - ti*(ti-1)/2
    int bid = blockIdx.x;
    int ti = (int)((2.f * NT + 1.f - sqrtf((float)((2 * NT + 1) * (2 * NT + 1) - 8 * bid))) * 0.5f);
    #define S_(x) ((x) * NT - (x) * ((x) - 1) / 2)
    while (S_(ti + 1) <= bid) ++ti;
    while (S_(ti) > bid) --ti;
    int tj = ti + (bid - S_(ti));
    #undef S_

    __shared__ bf16_t As[2][4096];   // 2 x 8 KB
    __shared__ bf16_t Bs[2][4096];
    __shared__ float wsum[4];

    int t = threadIdx.x, lane = t & 63, wv = t >> 6;
    int wr = wv >> 1, wc = wv & 1;

    // staging chunks: c = h*256+t; row r=c>>2, phys slot sq=c&3 holds logical
    // chunk q = sq ^ ((r>>1)&3)  -> 64 B-coalesced per row, swizzled in LDS
    const bf16_t* gA[2]; const bf16_t* gB[2];
    int ldsoff[2];
    #pragma unroll
    for (int h = 0; h < 2; ++h) {
        int c = h * 256 + t;
        int r = c >> 2, sq = c & 3;
        int q = sq ^ ((r >> 1) & 3);
        gA[h] = Zh + (size_t)(ti * BT + r) * DIM + q * 8;
        gB[h] = Zh + (size_t)(tj * BT + r) * DIM + q * 8;
        ldsoff[h] = (h * 256 + wv * 64) * 8;    // wave-uniform base (lane*16B implicit)
    }

    // fragment LDS element offsets
    int n16 = lane & 15, q16 = lane >> 4;
    int aoff[4], boff[4];
    #pragma unroll
    for (int aa = 0; aa < 4; ++aa) {
        int r = 16 * (wr * 4 + aa) + n16;
        aoff[aa] = (r * 4 + (q16 ^ ((r >> 1) & 3))) * 8;
    }
    #pragma unroll
    for (int bb = 0; bb < 4; ++bb) {
        int r = 16 * (wc * 4 + bb) + n16;
        boff[bb] = (r * 4 + (q16 ^ ((r >> 1) & 3))) * 8;
    }

    f32x4 accf[4][4];
    #pragma unroll
    for (int a = 0; a < 4; ++a)
        #pragma unroll
        for (int b = 0; b < 4; ++b)
            accf[a][b] = (f32x4){0.f, 0.f, 0.f, 0.f};

    // prologue: stage buffer 0, kt=0
    #pragma unroll
    for (int h = 0; h < 2; ++h) {
        gload_lds16(gA[h], &As[0][ldsoff[h]]);
        gload_lds16(gB[h], &Bs[0][ldsoff[h]]);
    }

    for (int kt = 0; kt < DIM; kt += BK) {
        int cur = (kt >> 5) & 1;
        __syncthreads();   // drains cur-buf loads (issued 1 iter ago) + prev ds_reads
        if (kt + BK < DIM) {
            #pragma unroll
            for (int h = 0; h < 2; ++h) {
                gload_lds16(gA[h] + kt + BK, &As[cur ^ 1][ldsoff[h]]);
                gload_lds16(gB[h] + kt + BK, &Bs[cur ^ 1][ldsoff[h]]);
            }
        }
        bf16x8 a[4], b[4];
        #pragma unroll
        for (int aa = 0; aa < 4; ++aa) a[aa] = *(const bf16x8*)(&As[cur][aoff[aa]]);
        #pragma unroll
        for (int bb = 0; bb < 4; ++bb) b[bb] = *(const bf16x8*)(&Bs[cur][boff[bb]]);
        #pragma unroll
        for (int aa = 0; aa < 4; ++aa)
            #pragma unroll
            for (int bb = 0; bb < 4; ++bb)
                accf[aa][bb] = __builtin_amdgcn_mfma_f32_16x16x32_bf16(
                    a[aa], b[bb], accf[aa][bb], 0, 0, 0);
    }

    // epilogue: D2 -> 5-bandwidth RBF via squaring chain (c_k halves per k)
    float c4 = cvals[4];
    int i0 = ti * BT + wr * 64;
    int j0 = tj * BT + wc * 64;

    float sqi[4][4], sqj[4];
    #pragma unroll
    for (int aa = 0; aa < 4; ++aa)
        #pragma unroll
        for (int r = 0; r < 4; ++r)
            sqi[aa][r] = sqrow[i0 + 16 * aa + q16 * 4 + r];
    #pragma unroll
    for (int bb = 0; bb < 4; ++bb)
        sqj[bb] = sqrow[j0 + 16 * bb + n16];

    float s_local = 0.f;
    #pragma unroll
    for (int aa = 0; aa < 4; ++aa) {
        #pragma unroll
        for (int bb = 0; bb < 4; ++bb) {
            #pragma unroll
            for (int r = 0; r < 4; ++r) {
                float d2 = fmaf(-2.f, accf[aa][bb][r], sqi[aa][r] + sqj[bb]);
                d2 = fmaxf(d2, 0.f);
                float e4 = EXP2F(d2 * c4);       // smallest |c|
                float e3 = e4 * e4;
                float e2 = e3 * e3;
                float e1 = e2 * e2;
                float e0 = e1 * e1;
                s_local += e4 + e3 + e2 + e1 + e0;
            }
        }
    }
    #pragma unroll
    for (int off = 32; off > 0; off >>= 1) s_local += __shfl_down(s_local, off);
    if (lane == 0) wsum[wv] = s_local;
    __syncthreads();
    if (t == 0) {
        float bs = wsum[0] + wsum[1] + wsum[2] + wsum[3];
        double si = (ti < NT / 2) ? 1.0 : -1.0;
        double sj = (tj < NT / 2) ? 1.0 : -1.0;
        double w = si * sj * ((ti == tj) ? 1.0 : 2.0);
        atomicAdd(acc, w * (double)bs);
        __threadfence();                          // acc-add visible before ticket
        unsigned old = atomicAdd(done, 1u);
        if (old == NB - 1) {                      // last block finalizes
            __threadfence();
            double tot = atomicAdd(acc, 0.0);     // atomic read
            out[0] = (float)(tot / ((double)NX * (double)NX));
        }
    }
}

extern "C" void kernel_launch(void* const* d_in, const int* in_sizes, int n_in,
                              void* d_out, int out_size, void* d_ws, size_t ws_size,
                              hipStream_t stream) {
    const float* X = (const float*)d_in[0];
    const float* Y = (const float*)d_in[1];
    float* out = (float*)d_out;

    float*    sqrow   = (float*)d_ws;
    float*    cvals   = (float*)((char*)d_ws + 32800 - 32);   // 32768
    // keep explicit offsets per layout comment:
    cvals             = (float*)((char*)d_ws + 32768);
    double*   acc     = (double*)((char*)d_ws + 32800);
    unsigned* done    = (unsigned*)((char*)d_ws + 32808);
    float*    colpart = (float*)((char*)d_ws + 32832);
    bf16_t*   Zh      = (bf16_t*)((char*)d_ws + 294976);

    k_prepall<<<2176, 256, 0, stream>>>(X, Y, Zh, sqrow, colpart);
    k_bw     <<<1, 256, 0, stream>>>(sqrow, colpart, cvals, acc, done);
    k_pair   <<<NB, 256, 0, stream>>>(Zh, sqrow, cvals, acc, done, out);
}